// Round 9
// baseline (94.691 us; speedup 1.0000x reference)
//
#include <hip/hip_runtime.h>
#include <stdint.h>

namespace {

constexpr int H = 512, W = 512;
constexpr int PLANE = H * W;
constexpr int IMG3 = 3 * PLANE;

constexpr float U_LO = -0.436f, U_HI = 0.436f;
constexpr float V_LO = -0.615f, V_HI = 0.615f;

constexpr int TW = 32, TH = 16;   // output tile per block (2 px/thread in x)
constexpr int CW = 40, CH = 24;   // staged tile incl. halo 4
constexpr int US = 13;            // u32 stride of U/V byte planes (52 B, 40 used)
constexpr int LUMS = 45;          // lumT f32 row stride

__device__ __forceinline__ int refl(int i, int n) {
    i = (i < 0) ? (-1 - i) : i;
    return (i >= n) ? (2 * n - 1 - i) : i;
}
__device__ __forceinline__ void cas(float& a, float& b) {
    float t = fminf(a, b); b = fmaxf(a, b); a = t;
}
__device__ __forceinline__ float med3(float a, float b, float c) {
    return fmaxf(fminf(a, b), fminf(fmaxf(a, b), c));
}
__device__ __forceinline__ float med9(float p0, float p1, float p2, float p3, float p4,
                                      float p5, float p6, float p7, float p8) {
    cas(p0, p1); cas(p1, p2); cas(p0, p1);
    cas(p3, p4); cas(p4, p5); cas(p3, p4);
    cas(p6, p7); cas(p7, p8); cas(p6, p7);
    float mx = fmaxf(fmaxf(p0, p3), p6);
    float md = med3(p1, p4, p7);
    float mn = fminf(fminf(p2, p5), p8);
    return med3(mx, md, mn);
}

// funnel shift: bytes of (w1:w0) starting at byte sh/8
__device__ __forceinline__ uint32_t fsh(uint32_t w1, uint32_t w0, uint32_t sh) {
    return (uint32_t)(((((uint64_t)w1) << 32) | w0) >> sh);  // -> v_alignbit_b32
}

__device__ __forceinline__ uint32_t sadacc(uint32_t t, uint32_t acc) {
#if __has_builtin(__builtin_amdgcn_sad_u8)
    return __builtin_amdgcn_sad_u8(t, 0u, acc);  // acc += 0x80 * popcnt_bytes
#else
    return acc + (t >> 7);                        // per-byte-lane counts
#endif
}
__device__ __forceinline__ uint32_t cntscaled(uint32_t acc) {
#if __has_builtin(__builtin_amdgcn_sad_u8)
    return acc;                                   // already 128*count
#else
    return ((acc * 0x01010101u) >> 24) << 7;      // normalize to 128*count
#endif
}

// gather one channel's A/B windows (81 bytes + 3 zero pads in 21 u32) for the
// horizontally-adjacent pixel pair from a byte plane
__device__ __forceinline__ void gather(const uint32_t* plane, int tx, int ty,
                                       uint32_t* PA, uint32_t* PB) {
    const uint32_t sh = (uint32_t)((tx & 1) << 4);  // 0 or 16
    uint32_t la01 = 0, la1 = 0, la2 = 0, lb01 = 0, lb1 = 0, lb2 = 0;
#pragma unroll
    for (int r = 0; r < 9; ++r) {
        const uint32_t* row = plane + (ty + r) * US + (tx >> 1);
        uint32_t w0 = row[0], w1 = row[1], w2 = row[2];
        PA[2 * r] = fsh(w1, w0, sh);
        PA[2 * r + 1] = fsh(w2, w1, sh);
        PB[2 * r] = fsh(w1, w0, sh + 8);
        PB[2 * r + 1] = fsh(w2, w1, sh + 8);
        uint32_t la = (w2 >> sh) & 0xFFu;         // A's 9th byte of row
        uint32_t lb = (w2 >> (sh + 8)) & 0xFFu;   // B's 9th byte of row
        if (r < 4)      { la01 |= la << (8 * r);       lb01 |= lb << (8 * r); }
        else if (r < 8) { la1  |= la << (8 * (r - 4)); lb1  |= lb << (8 * (r - 4)); }
        else            { la2 = la;                    lb2 = lb; }
    }
    PA[18] = la01; PA[19] = la1; PA[20] = la2;  // pads are 0x00 (always count)
    PB[18] = lb01; PB[19] = lb1; PB[20] = lb2;
}

// two interleaved 7-step rank selections (rank 40 of 81 + 3 pads -> count 44)
__device__ __forceinline__ void search2(const uint32_t* __restrict__ P0,
                                        const uint32_t* __restrict__ P1,
                                        uint32_t& k0, uint32_t& k1) {
    uint32_t lo0 = 0, lo1 = 0;
    // SWAR threshold word: per byte 0x80 + m, m starts at 63
    uint32_t c0 = 0xBFBFBFBFu, c1 = 0xBFBFBFBFu;
    const uint32_t T = 44u * 128u;
#pragma unroll
    for (int s = 64; s >= 1; s >>= 1) {
        uint32_t a0 = 0, a1 = 0;
#pragma unroll
        for (int i = 0; i < 21; ++i) {
            a0 = sadacc((c0 - P0[i]) & 0x80808080u, a0);
            a1 = sadacc((c1 - P1[i]) & 0x80808080u, a1);
        }
        bool r0 = cntscaled(a0) < T;  // median above m -> go right
        bool r1 = cntscaled(a1) < T;
        lo0 += r0 ? (uint32_t)s : 0u;
        lo1 += r1 ? (uint32_t)s : 0u;
        if (s > 1) {
            const uint32_t d = (uint32_t)(s >> 1) * 0x01010101u;  // compile-time
            c0 = r0 ? c0 + d : c0 - d;
            c1 = r1 ? c1 + d : c1 - d;
        }
    }
    k0 = lo0; k1 = lo1;
}

__global__ __launch_bounds__(256, 4) void denoise_kernel(const float* __restrict__ img,
                                                         float* __restrict__ out) {
    __shared__ uint32_t uP[CH * US];
    __shared__ uint32_t vP[CH * US];
    __shared__ float lumT[CH * LUMS];

    const int tid = threadIdx.x;
    const int tx = tid & 15, ty = tid >> 4;
    const int bx = blockIdx.x, by = blockIdx.y, bz = blockIdx.z;
    const float* __restrict__ base = img + (size_t)bz * IMG3;

    // --- staging: Y (f32) + quantized 7-bit U,V byte planes for 40x24 tile ---
    uint8_t* u8p = (uint8_t*)uP;
    uint8_t* v8p = (uint8_t*)vP;
    {
        int idx = tid;
#pragma unroll 4
        for (int it = 0; it < 4; ++it) {
            if (idx < CW * CH) {
                int r = idx / CW, c = idx - r * CW;
                int gy = refl(by * TH + r - 4, H);
                int gx = refl(bx * TW + c - 4, W);
                int o = gy * W + gx;
                float R = base[o], G = base[o + PLANE], B = base[o + 2 * PLANE];
                float Y = 0.299f * R + 0.587f * G + 0.114f * B;
                float U = -0.14713f * R - 0.28886f * G + 0.436f * B;
                float V = 0.615f * R - 0.51499f * G - 0.10001f * B;
                int ku = (int)((U - U_LO) * (128.0f / (U_HI - U_LO)));
                int kv = (int)((V - V_LO) * (128.0f / (V_HI - V_LO)));
                ku = min(max(ku, 0), 127);
                kv = min(max(kv, 0), 127);
                lumT[r * LUMS + c] = Y;
                u8p[r * (US * 4) + c] = (uint8_t)ku;
                v8p[r * (US * 4) + c] = (uint8_t)kv;
            }
            idx += 256;
        }
    }
    __syncthreads();

    // --- U channel: gather pair windows, interleaved 2-way selection ---
    uint32_t kUA, kUB, kVA, kVB;
    {
        uint32_t PA[21], PB[21];
        gather(uP, tx, ty, PA, PB);
        search2(PA, PB, kUA, kUB);
    }
    // --- V channel ---
    {
        uint32_t PA[21], PB[21];
        gather(vP, tx, ty, PA, PB);
        search2(PA, PB, kVA, kVB);
    }

    // --- 3x3 lum median for both pixels ---
    const float* lr0 = &lumT[(ty + 3) * LUMS + 2 * tx + 3];
    const float* lr1 = lr0 + LUMS;
    const float* lr2 = lr1 + LUMS;
    float a0 = lr0[0], a1 = lr0[1], a2 = lr0[2], a3 = lr0[3];
    float b0 = lr1[0], b1 = lr1[1], b2 = lr1[2], b3 = lr1[3];
    float c0 = lr2[0], c1 = lr2[1], c2 = lr2[2], c3 = lr2[3];
    float YmA = fminf(fmaxf(med9(a0, a1, a2, b0, b1, b2, c0, c1, c2), 0.0f), 1.0f);
    float YmB = fminf(fmaxf(med9(a1, a2, a3, b1, b2, b3, c1, c2, c3), 0.0f), 1.0f);

    // --- dequant (bin centers) + YUV->RGB + store ---
    const float us = (U_HI - U_LO) / 128.0f, vs = (V_HI - V_LO) / 128.0f;
    float UmA = U_LO + ((float)kUA + 0.5f) * us;
    float VmA = V_LO + ((float)kVA + 0.5f) * vs;
    float UmB = U_LO + ((float)kUB + 0.5f) * us;
    float VmB = V_LO + ((float)kVB + 0.5f) * vs;

    size_t o = (size_t)bz * IMG3 + (size_t)(by * TH + ty) * W + (bx * TW + 2 * tx);
    out[o] = YmA + 1.13983f * VmA;
    out[o + 1] = YmB + 1.13983f * VmB;
    out[o + PLANE] = YmA - 0.39465f * UmA - 0.5806f * VmA;
    out[o + PLANE + 1] = YmB - 0.39465f * UmB - 0.5806f * VmB;
    out[o + 2 * PLANE] = YmA + 2.03211f * UmA;
    out[o + 2 * PLANE + 1] = YmB + 2.03211f * UmB;
}

} // namespace

extern "C" void kernel_launch(void* const* d_in, const int* in_sizes, int n_in,
                              void* d_out, int out_size, void* d_ws, size_t ws_size,
                              hipStream_t stream) {
    const float* img = (const float*)d_in[0];
    float* out = (float*)d_out;
    int batch = in_sizes[0] / IMG3;  // = 4
    dim3 grid(W / TW, H / TH, batch);
    dim3 block(256);
    hipLaunchKernelGGL(denoise_kernel, grid, block, 0, stream, img, out);
}

// Round 10
// 87.404 us; speedup vs baseline: 1.0834x; 1.0834x over previous
//
#include <hip/hip_runtime.h>
#include <stdint.h>

namespace {

constexpr int H = 512, W = 512;
constexpr int PLANE = H * W;
constexpr int IMG3 = 3 * PLANE;

constexpr float U_LO = -0.436f, U_HI = 0.436f;
constexpr float V_LO = -0.615f, V_HI = 0.615f;

constexpr int TW = 32, TH = 16;   // output tile per block (2 px/thread in x)
constexpr int CW = 40, CH = 24;   // staged tile incl. halo 4
constexpr int US = 13;            // u32 stride of U/V byte planes (52 B)
constexpr int LUMS = 45;          // lumT f32 row stride

__device__ __forceinline__ int refl(int i, int n) {
    i = (i < 0) ? (-1 - i) : i;
    return (i >= n) ? (2 * n - 1 - i) : i;
}
__device__ __forceinline__ void cas(float& a, float& b) {
    float t = fminf(a, b); b = fmaxf(a, b); a = t;
}
__device__ __forceinline__ float med3(float a, float b, float c) {
    return fmaxf(fminf(a, b), fminf(fmaxf(a, b), c));
}
__device__ __forceinline__ float med9(float p0, float p1, float p2, float p3, float p4,
                                      float p5, float p6, float p7, float p8) {
    cas(p0, p1); cas(p1, p2); cas(p0, p1);
    cas(p3, p4); cas(p4, p5); cas(p3, p4);
    cas(p6, p7); cas(p7, p8); cas(p6, p7);
    float mx = fmaxf(fmaxf(p0, p3), p6);
    float md = med3(p1, p4, p7);
    float mn = fminf(fminf(p2, p5), p8);
    return med3(mx, md, mn);
}

__device__ __forceinline__ uint32_t fsh(uint32_t w1, uint32_t w0, uint32_t sh) {
    return (uint32_t)(((((uint64_t)w1) << 32) | w0) >> sh);  // v_alignbit_b32
}

__device__ __forceinline__ uint32_t sadacc(uint32_t t, uint32_t acc) {
#if __has_builtin(__builtin_amdgcn_sad_u8)
    return __builtin_amdgcn_sad_u8(t, 0u, acc);  // acc += 0x80 * #set-bytes
#else
    return acc + (t >> 7);
#endif
}
__device__ __forceinline__ uint32_t cntscaled(uint32_t acc) {
#if __has_builtin(__builtin_amdgcn_sad_u8)
    return acc;                                   // already 128*count
#else
    return ((acc * 0x01010101u) >> 24) << 7;
#endif
}

__device__ __forceinline__ uint32_t permb(uint32_t hi, uint32_t lo, uint32_t sel) {
#if __has_builtin(__builtin_amdgcn_perm)
    return __builtin_amdgcn_perm(hi, lo, sel);   // bytes 0-3 from lo, 4-7 from hi
#else
    uint32_t r = 0;
#pragma unroll
    for (int b = 0; b < 4; ++b) {
        uint32_t s = (sel >> (8 * b)) & 7u;
        uint32_t byte = ((s < 4u) ? (lo >> (8 * s)) : (hi >> (8 * (s - 4u)))) & 0xFFu;
        r |= byte << (8 * b);
    }
    return r;
#endif
}

// Lo bytes = bins 0,2,4,6 counts; Hi bytes = bins 1,3,5,7. Returns the coarse
// bin (0..7) where the rank-41 (of 81) element lives.
__device__ __forceinline__ uint32_t coarse_bin(uint32_t Lo, uint32_t Hi) {
    uint32_t w0 = permb(Hi, Lo, 0x05010400u);  // bytes: bin0,bin1,bin2,bin3
    uint32_t w1 = permb(Hi, Lo, 0x07030602u);  // bytes: bin4..bin7
    uint32_t c0 = w0 + (w0 << 8); c0 += c0 << 16;       // in-word prefix sums
    uint32_t c1 = w1 + (w1 << 8); c1 += c1 << 16;
    uint32_t t = c0 >> 24; t |= t << 8; t |= t << 16;   // broadcast total(w0)
    c1 += t;                                            // global cum (bytes <= 81)
    uint32_t f0 = (0xA8A8A8A8u - c0) & 0x80808080u;     // bit7: cum <= 40
    uint32_t f1 = (0xA8A8A8A8u - c1) & 0x80808080u;
    uint32_t s = sadacc(f1, sadacc(f0, 0u));
    return cntscaled(s) >> 7;                           // #bins with cum<41 = bin
}

// gather one channel's A/B windows (81 bytes + 3 zero pads in 21 u32)
__device__ __forceinline__ void gather(const uint32_t* plane, int tx, int ty,
                                       uint32_t* PA, uint32_t* PB) {
    const uint32_t sh = (uint32_t)((tx & 1) << 4);  // 0 or 16
    uint32_t la01 = 0, la1 = 0, la2 = 0, lb01 = 0, lb1 = 0, lb2 = 0;
#pragma unroll
    for (int r = 0; r < 9; ++r) {
        const uint32_t* row = plane + (ty + r) * US + (tx >> 1);
        uint32_t w0 = row[0], w1 = row[1], w2 = row[2];
        PA[2 * r] = fsh(w1, w0, sh);
        PA[2 * r + 1] = fsh(w2, w1, sh);
        PB[2 * r] = fsh(w1, w0, sh + 8);
        PB[2 * r + 1] = fsh(w2, w1, sh + 8);
        uint32_t la = (w2 >> sh) & 0xFFu;
        uint32_t lb = (w2 >> (sh + 8)) & 0xFFu;
        if (r < 4)      { la01 |= la << (8 * r);       lb01 |= lb << (8 * r); }
        else if (r < 8) { la1  |= la << (8 * (r - 4)); lb1  |= lb << (8 * (r - 4)); }
        else            { la2 = la;                    lb2 = lb; }
    }
    PA[18] = la01; PA[19] = la1; PA[20] = la2;  // pads 0x00 (always count; thr 44)
    PB[18] = lb01; PB[19] = lb1; PB[20] = lb2;
}

// two interleaved 4-step fine selections starting at coarse bins b0,b1
__device__ __forceinline__ void fine2(const uint32_t* __restrict__ P0,
                                      const uint32_t* __restrict__ P1,
                                      uint32_t b0, uint32_t b1,
                                      uint32_t& k0, uint32_t& k1) {
    uint32_t lo0 = b0 << 4, lo1 = b1 << 4;
    uint32_t t0 = lo0 + 7u; t0 |= t0 << 8; t0 |= t0 << 16;
    uint32_t t1 = lo1 + 7u; t1 |= t1 << 8; t1 |= t1 << 16;
    uint32_t c0 = t0 + 0x80808080u, c1 = t1 + 0x80808080u;
    const uint32_t T = 44u * 128u;
#pragma unroll
    for (int s = 8; s >= 1; s >>= 1) {
        uint32_t a0 = 0, a1 = 0;
#pragma unroll
        for (int i = 0; i < 21; ++i) {
            a0 = sadacc((c0 - P0[i]) & 0x80808080u, a0);
            a1 = sadacc((c1 - P1[i]) & 0x80808080u, a1);
        }
        bool r0 = cntscaled(a0) < T;
        bool r1 = cntscaled(a1) < T;
        lo0 += r0 ? (uint32_t)s : 0u;
        lo1 += r1 ? (uint32_t)s : 0u;
        if (s > 1) {
            const uint32_t d = (uint32_t)(s >> 1) * 0x01010101u;  // compile-time
            c0 = r0 ? c0 + d : c0 - d;
            c1 = r1 ? c1 + d : c1 - d;
        }
    }
    k0 = lo0; k1 = lo1;
}

__global__ __launch_bounds__(256, 4) void denoise_kernel(const float* __restrict__ img,
                                                         float* __restrict__ out) {
    __shared__ uint32_t uP[CH * US];
    __shared__ uint32_t vP[CH * US];
    __shared__ float lumT[CH * LUMS];
    __shared__ uint32_t histT[2][16][41];  // [ch][yo][x]: 8-bin nibble col-hist

    const int tid = threadIdx.x;
    const int tx = tid & 15, ty = tid >> 4;
    const int bx = blockIdx.x, by = blockIdx.y, bz = blockIdx.z;
    const float* __restrict__ base = img + (size_t)bz * IMG3;

    // --- staging: Y (f32) + quantized 7-bit U,V byte planes for 40x24 tile ---
    uint8_t* u8p = (uint8_t*)uP;
    uint8_t* v8p = (uint8_t*)vP;
    {
        int idx = tid;
#pragma unroll 4
        for (int it = 0; it < 4; ++it) {
            if (idx < CW * CH) {
                int r = idx / CW, c = idx - r * CW;
                int gy = refl(by * TH + r - 4, H);
                int gx = refl(bx * TW + c - 4, W);
                int o = gy * W + gx;
                float R = base[o], G = base[o + PLANE], B = base[o + 2 * PLANE];
                float Y = 0.299f * R + 0.587f * G + 0.114f * B;
                float U = -0.14713f * R - 0.28886f * G + 0.436f * B;
                float V = 0.615f * R - 0.51499f * G - 0.10001f * B;
                int ku = (int)((U - U_LO) * (128.0f / (U_HI - U_LO)));
                int kv = (int)((V - V_LO) * (128.0f / (V_HI - V_LO)));
                ku = min(max(ku, 0), 127);
                kv = min(max(kv, 0), 127);
                lumT[r * LUMS + c] = Y;
                u8p[r * (US * 4) + c] = (uint8_t)ku;
                v8p[r * (US * 4) + c] = (uint8_t)kv;
            }
            idx += 256;
        }
    }
    __syncthreads();

    // --- build column histograms: 2ch x 40 cols x 16 row-windows ---
    if (tid < 240) {
        int colch = tid % 80;           // 80 column-channels
        int seg = tid / 80;             // 0..2 -> yo segments 0-5, 6-10, 11-15
        int yo0 = (seg == 0) ? 0 : (seg == 1 ? 6 : 11);
        int nyo = (seg == 0) ? 6 : 5;
        int ch = (colch >= 40) ? 1 : 0;
        int x = colch - ch * 40;
        const uint8_t* p = (const uint8_t*)(ch ? vP : uP) + x + 52 * yo0;
        uint32_t h = 0;
#pragma unroll
        for (int r = 0; r < 9; ++r) {
            uint32_t k = p[52 * r];
            h += 1u << (((k >> 4) & 7u) << 2);
        }
        histT[ch][yo0][x] = h;
        for (int i = 1; i < nyo; ++i) {   // slide window down the column
            uint32_t ko = p[52 * (i - 1)];
            uint32_t ki = p[52 * (i + 8)];
            h -= 1u << (((ko >> 4) & 7u) << 2);
            h += 1u << (((ki >> 4) & 7u) << 2);
            histT[ch][yo0 + i][x] = h;
        }
    }
    __syncthreads();

    // --- coarse bins for all four selections (pair shares cols 1..8) ---
    uint32_t binUA, binUB, binVA, binVB;
#pragma unroll
    for (int ch = 0; ch < 2; ++ch) {
        const uint32_t* hrow = &histT[ch][ty][2 * tx];
        uint32_t sLo = 0, sHi = 0;
#pragma unroll
        for (int c = 1; c <= 8; ++c) {
            uint32_t h = hrow[c];
            sLo += h & 0x0F0F0F0Fu;
            sHi += (h >> 4) & 0x0F0F0F0Fu;
        }
        uint32_t h0 = hrow[0], h9 = hrow[9];
        uint32_t bA = coarse_bin(sLo + (h0 & 0x0F0F0F0Fu),
                                 sHi + ((h0 >> 4) & 0x0F0F0F0Fu));
        uint32_t bB = coarse_bin(sLo + (h9 & 0x0F0F0F0Fu),
                                 sHi + ((h9 >> 4) & 0x0F0F0F0Fu));
        if (ch == 0) { binUA = bA; binUB = bB; }
        else         { binVA = bA; binVB = bB; }
    }

    // --- fine phase: 4 SWAR steps per selection on the byte windows ---
    uint32_t kUA, kUB, kVA, kVB;
    {
        uint32_t PA[21], PB[21];
        gather(uP, tx, ty, PA, PB);
        fine2(PA, PB, binUA, binUB, kUA, kUB);
    }
    {
        uint32_t PA[21], PB[21];
        gather(vP, tx, ty, PA, PB);
        fine2(PA, PB, binVA, binVB, kVA, kVB);
    }

    // --- 3x3 lum median for both pixels ---
    const float* lr0 = &lumT[(ty + 3) * LUMS + 2 * tx + 3];
    const float* lr1 = lr0 + LUMS;
    const float* lr2 = lr1 + LUMS;
    float a0 = lr0[0], a1 = lr0[1], a2 = lr0[2], a3 = lr0[3];
    float b0 = lr1[0], b1 = lr1[1], b2 = lr1[2], b3 = lr1[3];
    float c0 = lr2[0], c1 = lr2[1], c2 = lr2[2], c3 = lr2[3];
    float YmA = fminf(fmaxf(med9(a0, a1, a2, b0, b1, b2, c0, c1, c2), 0.0f), 1.0f);
    float YmB = fminf(fmaxf(med9(a1, a2, a3, b1, b2, b3, c1, c2, c3), 0.0f), 1.0f);

    // --- dequant (bin centers) + YUV->RGB + store ---
    const float us = (U_HI - U_LO) / 128.0f, vs = (V_HI - V_LO) / 128.0f;
    float UmA = U_LO + ((float)kUA + 0.5f) * us;
    float VmA = V_LO + ((float)kVA + 0.5f) * vs;
    float UmB = U_LO + ((float)kUB + 0.5f) * us;
    float VmB = V_LO + ((float)kVB + 0.5f) * vs;

    size_t o = (size_t)bz * IMG3 + (size_t)(by * TH + ty) * W + (bx * TW + 2 * tx);
    out[o] = YmA + 1.13983f * VmA;
    out[o + 1] = YmB + 1.13983f * VmB;
    out[o + PLANE] = YmA - 0.39465f * UmA - 0.5806f * VmA;
    out[o + PLANE + 1] = YmB - 0.39465f * UmB - 0.5806f * VmB;
    out[o + 2 * PLANE] = YmA + 2.03211f * UmA;
    out[o + 2 * PLANE + 1] = YmB + 2.03211f * UmB;
}

} // namespace

extern "C" void kernel_launch(void* const* d_in, const int* in_sizes, int n_in,
                              void* d_out, int out_size, void* d_ws, size_t ws_size,
                              hipStream_t stream) {
    const float* img = (const float*)d_in[0];
    float* out = (float*)d_out;
    int batch = in_sizes[0] / IMG3;  // = 4
    dim3 grid(W / TW, H / TH, batch);
    dim3 block(256);
    hipLaunchKernelGGL(denoise_kernel, grid, block, 0, stream, img, out);
}

// Round 11
// 82.053 us; speedup vs baseline: 1.1540x; 1.0652x over previous
//
#include <hip/hip_runtime.h>
#include <stdint.h>

namespace {

constexpr int H = 512, W = 512;
constexpr int PLANE = H * W;
constexpr int IMG3 = 3 * PLANE;

constexpr float U_LO = -0.436f, U_HI = 0.436f;
constexpr float V_LO = -0.615f, V_HI = 0.615f;
constexpr float NBINS = 64.0f;   // 6-bit keys

constexpr int TW = 64, TH = 16;  // output tile per block (4 px/thread in x)
constexpr int CW = 72, CH = 24;  // staged tile incl. halo 4
constexpr int US = 19;           // u32 stride of U/V byte planes (76 B, 72 used)
constexpr int LUMS = 73;         // lumT f32 row stride

__device__ __forceinline__ int refl(int i, int n) {
    i = (i < 0) ? (-1 - i) : i;
    return (i >= n) ? (2 * n - 1 - i) : i;
}
__device__ __forceinline__ void cas(float& a, float& b) {
    float t = fminf(a, b); b = fmaxf(a, b); a = t;
}
__device__ __forceinline__ float med3(float a, float b, float c) {
    return fmaxf(fminf(a, b), fminf(fmaxf(a, b), c));
}

__device__ __forceinline__ uint32_t fsh(uint32_t w1, uint32_t w0, uint32_t sh) {
    return (uint32_t)(((((uint64_t)w1) << 32) | w0) >> sh);  // v_alignbit_b32
}

__device__ __forceinline__ uint32_t sadacc(uint32_t t, uint32_t acc) {
#if __has_builtin(__builtin_amdgcn_sad_u8)
    return __builtin_amdgcn_sad_u8(t, 0u, acc);  // acc += 0x80 * #set-bytes
#else
    return acc + (t >> 7);
#endif
}
__device__ __forceinline__ uint32_t cntscaled(uint32_t acc) {
#if __has_builtin(__builtin_amdgcn_sad_u8)
    return acc;                                   // already 128*count
#else
    return ((acc * 0x01010101u) >> 24) << 7;
#endif
}

__device__ __forceinline__ uint32_t permb(uint32_t hi, uint32_t lo, uint32_t sel) {
#if __has_builtin(__builtin_amdgcn_perm)
    return __builtin_amdgcn_perm(hi, lo, sel);
#else
    uint32_t r = 0;
#pragma unroll
    for (int b = 0; b < 4; ++b) {
        uint32_t s = (sel >> (8 * b)) & 7u;
        uint32_t byte = ((s < 4u) ? (lo >> (8 * s)) : (hi >> (8 * (s - 4u)))) & 0xFFu;
        r |= byte << (8 * b);
    }
    return r;
#endif
}

// Lo bytes = bins 0,2,4,6; Hi bytes = bins 1,3,5,7 (counts <= 81).
// Returns coarse bin (0..7) containing 0-based rank 40.
__device__ __forceinline__ uint32_t coarse_bin(uint32_t Lo, uint32_t Hi) {
    uint32_t w0 = permb(Hi, Lo, 0x05010400u);  // bins 0..3
    uint32_t w1 = permb(Hi, Lo, 0x07030602u);  // bins 4..7
    uint32_t c0 = w0 + (w0 << 8); c0 += c0 << 16;
    uint32_t c1 = w1 + (w1 << 8); c1 += c1 << 16;
    uint32_t t = c0 >> 24; t |= t << 8; t |= t << 16;
    c1 += t;
    uint32_t f0 = (0xA8A8A8A8u - c0) & 0x80808080u;  // bit7: cum <= 40
    uint32_t f1 = (0xA8A8A8A8u - c1) & 0x80808080u;
    uint32_t s = sadacc(f1, sadacc(f0, 0u));
    return cntscaled(s) >> 7;
}

// build one pixel's 21-word window (81 bytes + 3 zero pads) from 27 row words
__device__ __forceinline__ void buildP(const uint32_t* rw, uint32_t sh, uint32_t* P) {
    uint32_t p01 = 0, p1 = 0, p2v = 0;
#pragma unroll
    for (int r = 0; r < 9; ++r) {
        uint32_t w0 = rw[3 * r], w1 = rw[3 * r + 1], w2 = rw[3 * r + 2];
        P[2 * r]     = fsh(w1, w0, sh);   // sh==0 folds to w0
        P[2 * r + 1] = fsh(w2, w1, sh);
        uint32_t l = (w2 >> sh) & 0xFFu;  // 9th byte of the window row
        if (r < 4)      p01 |= l << (8 * r);
        else if (r < 8) p1  |= l << (8 * (r - 4));
        else            p2v = l;
    }
    P[18] = p01; P[19] = p1; P[20] = p2v;  // pads 0x00 always count -> thr 44
}

// two interleaved 3-step fine selections over 8 values from coarse bins b0,b1
__device__ __forceinline__ void fine2(const uint32_t* __restrict__ P0,
                                      const uint32_t* __restrict__ P1,
                                      uint32_t b0, uint32_t b1,
                                      uint32_t& k0, uint32_t& k1) {
    uint32_t lo0 = b0 << 3, lo1 = b1 << 3;
    uint32_t t0 = lo0 + 3u; t0 |= t0 << 8; t0 |= t0 << 16;
    uint32_t t1 = lo1 + 3u; t1 |= t1 << 8; t1 |= t1 << 16;
    uint32_t c0 = t0 + 0x80808080u, c1 = t1 + 0x80808080u;
    const uint32_t T = 44u * 128u;  // rank 40 + 1 (0-based->count) + 3 pads
#pragma unroll
    for (int s = 4; s >= 1; s >>= 1) {
        uint32_t a0 = 0, a1 = 0;
#pragma unroll
        for (int i = 0; i < 21; ++i) {
            a0 = sadacc((c0 - P0[i]) & 0x80808080u, a0);
            a1 = sadacc((c1 - P1[i]) & 0x80808080u, a1);
        }
        bool r0 = cntscaled(a0) < T;
        bool r1 = cntscaled(a1) < T;
        lo0 += r0 ? (uint32_t)s : 0u;
        lo1 += r1 ? (uint32_t)s : 0u;
        if (s > 1) {
            const uint32_t d = (uint32_t)(s >> 1) * 0x01010101u;  // compile-time
            c0 = r0 ? c0 + d : c0 - d;
            c1 = r1 ? c1 + d : c1 - d;
        }
    }
    k0 = lo0; k1 = lo1;
}

__global__ __launch_bounds__(256, 4) void denoise_kernel(const float* __restrict__ img,
                                                         float* __restrict__ out) {
    __shared__ uint32_t uP[CH * US];       // U byte plane (6-bit keys)
    __shared__ uint32_t vP[CH * US];       // V byte plane
    __shared__ float lumT[CH * LUMS];
    __shared__ uint32_t histT[2][16][72];  // [ch][yo][x]: 8-bin nibble col-hist

    const int tid = threadIdx.x;
    const int tx = tid & 15, ty = tid >> 4;
    const int bx = blockIdx.x, by = blockIdx.y, bz = blockIdx.z;
    const float* __restrict__ base = img + (size_t)bz * IMG3;

    uint8_t* u8p = (uint8_t*)uP;
    uint8_t* v8p = (uint8_t*)vP;

    // --- staging: Y + quantized 6-bit U,V byte planes for 72x24 tile ---
    {
        int idx = tid;
#pragma unroll 7
        for (int it = 0; it < 7; ++it) {
            if (idx < CW * CH) {
                int r = idx / CW, c = idx - r * CW;
                int gy = refl(by * TH + r - 4, H);
                int gx = refl(bx * TW + c - 4, W);
                int o = gy * W + gx;
                float R = base[o], G = base[o + PLANE], B = base[o + 2 * PLANE];
                float Y = 0.299f * R + 0.587f * G + 0.114f * B;
                float U = -0.14713f * R - 0.28886f * G + 0.436f * B;
                float V = 0.615f * R - 0.51499f * G - 0.10001f * B;
                int ku = (int)((U - U_LO) * (NBINS / (U_HI - U_LO)));
                int kv = (int)((V - V_LO) * (NBINS / (V_HI - V_LO)));
                ku = min(max(ku, 0), 63);
                kv = min(max(kv, 0), 63);
                lumT[r * LUMS + c] = Y;
                u8p[r * (US * 4) + c] = (uint8_t)ku;
                v8p[r * (US * 4) + c] = (uint8_t)kv;
            }
            idx += 256;
        }
    }
    __syncthreads();

    // --- column histograms: 2ch x 72 cols, 16 sliding row-windows each ---
    if (tid < 144) {
        int ch = (tid >= 72) ? 1 : 0;
        int x = tid - ch * 72;
        const uint8_t* p = (ch ? v8p : u8p) + x;
        uint32_t h = 0;
#pragma unroll
        for (int r = 0; r < 9; ++r)
            h += 1u << (((p[76 * r] >> 3) & 7u) << 2);
        histT[ch][0][x] = h;
        for (int i = 1; i < 16; ++i) {
            h -= 1u << (((p[76 * (i - 1)] >> 3) & 7u) << 2);
            h += 1u << (((p[76 * (i + 8)] >> 3) & 7u) << 2);
            histT[ch][i][x] = h;
        }
    }
    __syncthreads();

    // --- coarse bins for 4 px x 2 channels (shared-core merge, cols 3..8) ---
    uint32_t bins[2][4];
#pragma unroll
    for (int ch = 0; ch < 2; ++ch) {
        const uint32_t* hrow = &histT[ch][ty][4 * tx];
        uint32_t sLo = 0, sHi = 0;
#pragma unroll
        for (int c = 3; c <= 8; ++c) {
            uint32_t h = hrow[c];
            sLo += h & 0x0F0F0F0Fu;
            sHi += (h >> 4) & 0x0F0F0F0Fu;
        }
        uint32_t e0 = hrow[0], e1 = hrow[1], e2 = hrow[2];
        uint32_t e9 = hrow[9], e10 = hrow[10], e11 = hrow[11];
        uint32_t L0 = e0 & 0x0F0F0F0Fu, H0 = (e0 >> 4) & 0x0F0F0F0Fu;
        uint32_t L1 = e1 & 0x0F0F0F0Fu, H1 = (e1 >> 4) & 0x0F0F0F0Fu;
        uint32_t L2 = e2 & 0x0F0F0F0Fu, H2 = (e2 >> 4) & 0x0F0F0F0Fu;
        uint32_t L9 = e9 & 0x0F0F0F0Fu, H9 = (e9 >> 4) & 0x0F0F0F0Fu;
        uint32_t L10 = e10 & 0x0F0F0F0Fu, H10 = (e10 >> 4) & 0x0F0F0F0Fu;
        uint32_t L11 = e11 & 0x0F0F0F0Fu, H11 = (e11 >> 4) & 0x0F0F0F0Fu;
        bins[ch][0] = coarse_bin(sLo + L0 + L1 + L2,  sHi + H0 + H1 + H2);
        bins[ch][1] = coarse_bin(sLo + L1 + L2 + L9,  sHi + H1 + H2 + H9);
        bins[ch][2] = coarse_bin(sLo + L2 + L9 + L10, sHi + H2 + H9 + H10);
        bins[ch][3] = coarse_bin(sLo + L9 + L10 + L11, sHi + H9 + H10 + H11);
    }

    // --- fine phase: per channel, read 27 row words once, 4 selections ---
    uint32_t kk[2][4];
#pragma unroll
    for (int ch = 0; ch < 2; ++ch) {
        const uint32_t* plane = ch ? vP : uP;
        uint32_t rw[27];
#pragma unroll
        for (int r = 0; r < 9; ++r) {
            const uint32_t* row = plane + (ty + r) * US + tx;
            rw[3 * r] = row[0]; rw[3 * r + 1] = row[1]; rw[3 * r + 2] = row[2];
        }
        uint32_t P0[21], P1[21];
        buildP(rw, 0u, P0);
        buildP(rw, 8u, P1);
        fine2(P0, P1, bins[ch][0], bins[ch][1], kk[ch][0], kk[ch][1]);
        buildP(rw, 16u, P0);
        buildP(rw, 24u, P1);
        fine2(P0, P1, bins[ch][2], bins[ch][3], kk[ch][2], kk[ch][3]);
    }

    // --- 3x3 lum median for 4 px via shared column sorts (cols 4tx+3..4tx+8) ---
    float Ym[4];
    {
        const float* lp = &lumT[(ty + 3) * LUMS + 4 * tx + 3];
        float lo[6], mi[6], hi[6];
#pragma unroll
        for (int j = 0; j < 6; ++j) {
            float a = lp[j], b = lp[j + LUMS], c = lp[j + 2 * LUMS];
            cas(a, b); cas(b, c); cas(a, b);
            lo[j] = a; mi[j] = b; hi[j] = c;
        }
#pragma unroll
        for (int p = 0; p < 4; ++p) {
            float mx = fmaxf(fmaxf(lo[p], lo[p + 1]), lo[p + 2]);
            float md = med3(mi[p], mi[p + 1], mi[p + 2]);
            float mn = fminf(fminf(hi[p], hi[p + 1]), hi[p + 2]);
            Ym[p] = fminf(fmaxf(med3(mx, md, mn), 0.0f), 1.0f);
        }
    }

    // --- dequant (bin centers) + YUV->RGB + float4 stores ---
    const float us = (U_HI - U_LO) / NBINS, vs = (V_HI - V_LO) / NBINS;
    float4 Rq, Gq, Bq;
    float* Rp = &Rq.x; float* Gp = &Gq.x; float* Bp = &Bq.x;
#pragma unroll
    for (int p = 0; p < 4; ++p) {
        float Um = U_LO + ((float)kk[0][p] + 0.5f) * us;
        float Vm = V_LO + ((float)kk[1][p] + 0.5f) * vs;
        Rp[p] = Ym[p] + 1.13983f * Vm;
        Gp[p] = Ym[p] - 0.39465f * Um - 0.5806f * Vm;
        Bp[p] = Ym[p] + 2.03211f * Um;
    }
    size_t o = (size_t)bz * IMG3 + (size_t)(by * TH + ty) * W + (bx * TW + 4 * tx);
    *(float4*)(out + o) = Rq;
    *(float4*)(out + o + PLANE) = Gq;
    *(float4*)(out + o + 2 * PLANE) = Bq;
}

} // namespace

extern "C" void kernel_launch(void* const* d_in, const int* in_sizes, int n_in,
                              void* d_out, int out_size, void* d_ws, size_t ws_size,
                              hipStream_t stream) {
    const float* img = (const float*)d_in[0];
    float* out = (float*)d_out;
    int batch = in_sizes[0] / IMG3;  // = 4
    dim3 grid(W / TW, H / TH, batch);
    dim3 block(256);
    hipLaunchKernelGGL(denoise_kernel, grid, block, 0, stream, img, out);
}

// Round 12
// 81.241 us; speedup vs baseline: 1.1656x; 1.0100x over previous
//
#include <hip/hip_runtime.h>
#include <stdint.h>

namespace {

constexpr int H = 512, W = 512;
constexpr int PLANE = H * W;
constexpr int IMG3 = 3 * PLANE;

constexpr float U_LO = -0.436f, U_HI = 0.436f;
constexpr float V_LO = -0.615f, V_HI = 0.615f;
constexpr float NBINS = 64.0f;   // 6-bit keys

constexpr int TW = 64, TH = 16;  // output tile per block (4 px/thread in x)
constexpr int CW = 72, CH = 24;  // staged tile incl. halo 4
constexpr int US = 19;           // u32 stride of U/V byte planes (76 B, 72 used)
constexpr int LUMS = 73;         // lumT f32 row stride

__device__ __forceinline__ int refl(int i, int n) {
    i = (i < 0) ? (-1 - i) : i;
    return (i >= n) ? (2 * n - 1 - i) : i;
}
__device__ __forceinline__ void cas(float& a, float& b) {
    float t = fminf(a, b); b = fmaxf(a, b); a = t;
}
__device__ __forceinline__ float med3(float a, float b, float c) {
    return fmaxf(fminf(a, b), fminf(fmaxf(a, b), c));
}

__device__ __forceinline__ uint32_t fsh(uint32_t w1, uint32_t w0, uint32_t sh) {
    return (uint32_t)(((((uint64_t)w1) << 32) | w0) >> sh);  // v_alignbit_b32
}

__device__ __forceinline__ uint32_t sadacc(uint32_t t, uint32_t acc) {
#if __has_builtin(__builtin_amdgcn_sad_u8)
    return __builtin_amdgcn_sad_u8(t, 0u, acc);  // acc += 0x80 * #set-bytes
#else
    return acc + (t >> 7);
#endif
}
__device__ __forceinline__ uint32_t cntscaled(uint32_t acc) {
#if __has_builtin(__builtin_amdgcn_sad_u8)
    return acc;                                   // already 128*count
#else
    return ((acc * 0x01010101u) >> 24) << 7;
#endif
}

__device__ __forceinline__ uint32_t permb(uint32_t hi, uint32_t lo, uint32_t sel) {
#if __has_builtin(__builtin_amdgcn_perm)
    return __builtin_amdgcn_perm(hi, lo, sel);
#else
    uint32_t r = 0;
#pragma unroll
    for (int b = 0; b < 4; ++b) {
        uint32_t s = (sel >> (8 * b)) & 7u;
        uint32_t byte = ((s < 4u) ? (lo >> (8 * s)) : (hi >> (8 * (s - 4u)))) & 0xFFu;
        r |= byte << (8 * b);
    }
    return r;
#endif
}

// 16-bin coarse select. ELo bytes = bins 0,2,4,6; EHi = 1,3,5,7;
// OLo = 8,10,12,14; OHi = 9,11,13,15 (counts <= 81).
// Returns coarse bin (0..15) containing 0-based rank 40.
__device__ __forceinline__ uint32_t coarse_bin16(uint32_t ELo, uint32_t EHi,
                                                 uint32_t OLo, uint32_t OHi) {
    uint32_t w0 = permb(EHi, ELo, 0x05010400u);  // bins 0..3
    uint32_t w1 = permb(EHi, ELo, 0x07030602u);  // bins 4..7
    uint32_t w2 = permb(OHi, OLo, 0x05010400u);  // bins 8..11
    uint32_t w3 = permb(OHi, OLo, 0x07030602u);  // bins 12..15
    uint32_t c0 = w0 + (w0 << 8); c0 += c0 << 16;  // in-word prefix sums
    uint32_t c1 = w1 + (w1 << 8); c1 += c1 << 16;
    uint32_t c2 = w2 + (w2 << 8); c2 += c2 << 16;
    uint32_t c3 = w3 + (w3 << 8); c3 += c3 << 16;
    uint32_t t = (c0 >> 24) * 0x01010101u;          // cascade running totals
    c1 += t;
    t = (c1 >> 24) * 0x01010101u;
    c2 += t;
    t = (c2 >> 24) * 0x01010101u;
    c3 += t;
    uint32_t f0 = (0xA8A8A8A8u - c0) & 0x80808080u;  // bit7: cum <= 40
    uint32_t f1 = (0xA8A8A8A8u - c1) & 0x80808080u;
    uint32_t f2 = (0xA8A8A8A8u - c2) & 0x80808080u;
    uint32_t f3 = (0xA8A8A8A8u - c3) & 0x80808080u;
    uint32_t s = sadacc(f3, sadacc(f2, sadacc(f1, sadacc(f0, 0u))));
    return cntscaled(s) >> 7;                        // #bins with cum<41 = bin
}

// build one pixel's 21-word window (81 bytes + 3 zero pads) from 27 row words
__device__ __forceinline__ void buildP(const uint32_t* rw, uint32_t sh, uint32_t* P) {
    uint32_t p01 = 0, p1 = 0, p2v = 0;
#pragma unroll
    for (int r = 0; r < 9; ++r) {
        uint32_t w0 = rw[3 * r], w1 = rw[3 * r + 1], w2 = rw[3 * r + 2];
        P[2 * r]     = fsh(w1, w0, sh);   // sh==0 folds to w0
        P[2 * r + 1] = fsh(w2, w1, sh);
        uint32_t l = (w2 >> sh) & 0xFFu;  // 9th byte of the window row
        if (r < 4)      p01 |= l << (8 * r);
        else if (r < 8) p1  |= l << (8 * (r - 4));
        else            p2v = l;
    }
    P[18] = p01; P[19] = p1; P[20] = p2v;  // pads 0x00 always count -> thr 44
}

// two interleaved 2-step fine selections over 4 values from coarse bins b0,b1
__device__ __forceinline__ void fine2(const uint32_t* __restrict__ P0,
                                      const uint32_t* __restrict__ P1,
                                      uint32_t b0, uint32_t b1,
                                      uint32_t& k0, uint32_t& k1) {
    uint32_t lo0 = b0 << 2, lo1 = b1 << 2;
    uint32_t t0 = (lo0 + 1u) * 0x01010101u;
    uint32_t t1 = (lo1 + 1u) * 0x01010101u;
    uint32_t c0 = t0 + 0x80808080u, c1 = t1 + 0x80808080u;
    const uint32_t T = 44u * 128u;  // rank 40 + 1 (0-based->count) + 3 pads
#pragma unroll
    for (int s = 2; s >= 1; s >>= 1) {
        uint32_t a0 = 0, a1 = 0;
#pragma unroll
        for (int i = 0; i < 21; ++i) {
            a0 = sadacc((c0 - P0[i]) & 0x80808080u, a0);
            a1 = sadacc((c1 - P1[i]) & 0x80808080u, a1);
        }
        bool r0 = cntscaled(a0) < T;
        bool r1 = cntscaled(a1) < T;
        lo0 += r0 ? (uint32_t)s : 0u;
        lo1 += r1 ? (uint32_t)s : 0u;
        if (s > 1) {
            const uint32_t d = 0x01010101u;  // s/2 = 1
            c0 = r0 ? c0 + d : c0 - d;
            c1 = r1 ? c1 + d : c1 - d;
        }
    }
    k0 = lo0; k1 = lo1;
}

__global__ __launch_bounds__(256, 4) void denoise_kernel(const float* __restrict__ img,
                                                         float* __restrict__ out) {
    __shared__ uint32_t uP[CH * US];          // U byte plane (6-bit keys)
    __shared__ uint32_t vP[CH * US];          // V byte plane
    __shared__ float lumT[CH * LUMS];
    __shared__ uint32_t histT[2][16][72][2];  // [ch][yo][x][w]: 16-bin nibble hist

    const int tid = threadIdx.x;
    const int tx = tid & 15, ty = tid >> 4;
    const int bx = blockIdx.x, by = blockIdx.y, bz = blockIdx.z;
    const float* __restrict__ base = img + (size_t)bz * IMG3;

    uint8_t* u8p = (uint8_t*)uP;
    uint8_t* v8p = (uint8_t*)vP;

    // --- staging: Y + quantized 6-bit U,V byte planes for 72x24 tile ---
    {
        int idx = tid;
#pragma unroll 7
        for (int it = 0; it < 7; ++it) {
            if (idx < CW * CH) {
                int r = idx / CW, c = idx - r * CW;
                int gy = refl(by * TH + r - 4, H);
                int gx = refl(bx * TW + c - 4, W);
                int o = gy * W + gx;
                float R = base[o], G = base[o + PLANE], B = base[o + 2 * PLANE];
                float Y = 0.299f * R + 0.587f * G + 0.114f * B;
                float U = -0.14713f * R - 0.28886f * G + 0.436f * B;
                float V = 0.615f * R - 0.51499f * G - 0.10001f * B;
                int ku = (int)((U - U_LO) * (NBINS / (U_HI - U_LO)));
                int kv = (int)((V - V_LO) * (NBINS / (V_HI - V_LO)));
                ku = min(max(ku, 0), 63);
                kv = min(max(kv, 0), 63);
                lumT[r * LUMS + c] = Y;
                u8p[r * (US * 4) + c] = (uint8_t)ku;
                v8p[r * (US * 4) + c] = (uint8_t)kv;
            }
            idx += 256;
        }
    }
    __syncthreads();

    // --- column histograms: 2ch x 72 cols, 16 sliding 9-row windows each ---
    if (tid < 144) {
        int ch = (tid >= 72) ? 1 : 0;
        int x = tid - ch * 72;
        const uint8_t* p = (ch ? v8p : u8p) + x;
        uint32_t h0 = 0, h1 = 0;
#pragma unroll
        for (int r = 0; r < 9; ++r) {
            uint32_t b = p[76 * r] >> 2;                 // bin 0..15
            uint32_t d = 1u << ((b & 7u) << 2);
            if (b & 8u) h1 += d; else h0 += d;
        }
        histT[ch][0][x][0] = h0;
        histT[ch][0][x][1] = h1;
        for (int i = 1; i < 16; ++i) {
            uint32_t bo = p[76 * (i - 1)] >> 2;
            uint32_t dob = 1u << ((bo & 7u) << 2);
            if (bo & 8u) h1 -= dob; else h0 -= dob;
            uint32_t bi = p[76 * (i + 8)] >> 2;
            uint32_t dib = 1u << ((bi & 7u) << 2);
            if (bi & 8u) h1 += dib; else h0 += dib;
            histT[ch][i][x][0] = h0;
            histT[ch][i][x][1] = h1;
        }
    }
    __syncthreads();

    // --- coarse bins for 4 px x 2 channels (shared-core merge, cols 3..8) ---
    uint32_t bins[2][4];
    const uint32_t NM = 0x0F0F0F0Fu;
#pragma unroll
    for (int ch = 0; ch < 2; ++ch) {
        const uint32_t* hrow = &histT[ch][ty][4 * tx][0];
        uint32_t sEL = 0, sEH = 0, sOL = 0, sOH = 0;
#pragma unroll
        for (int c = 3; c <= 8; ++c) {
            uint32_t h0 = hrow[2 * c], h1 = hrow[2 * c + 1];
            sEL += h0 & NM; sEH += (h0 >> 4) & NM;
            sOL += h1 & NM; sOH += (h1 >> 4) & NM;
        }
        uint32_t EL[6], EH[6], OL[6], OH[6];  // edge cols 0,1,2,9,10,11
#pragma unroll
        for (int j = 0; j < 6; ++j) {
            int c = (j < 3) ? j : (j + 6);
            uint32_t h0 = hrow[2 * c], h1 = hrow[2 * c + 1];
            EL[j] = h0 & NM; EH[j] = (h0 >> 4) & NM;
            OL[j] = h1 & NM; OH[j] = (h1 >> 4) & NM;
        }
        bins[ch][0] = coarse_bin16(sEL + EL[0] + EL[1] + EL[2],
                                   sEH + EH[0] + EH[1] + EH[2],
                                   sOL + OL[0] + OL[1] + OL[2],
                                   sOH + OH[0] + OH[1] + OH[2]);
        bins[ch][1] = coarse_bin16(sEL + EL[1] + EL[2] + EL[3],
                                   sEH + EH[1] + EH[2] + EH[3],
                                   sOL + OL[1] + OL[2] + OL[3],
                                   sOH + OH[1] + OH[2] + OH[3]);
        bins[ch][2] = coarse_bin16(sEL + EL[2] + EL[3] + EL[4],
                                   sEH + EH[2] + EH[3] + EH[4],
                                   sOL + OL[2] + OL[3] + OL[4],
                                   sOH + OH[2] + OH[3] + OH[4]);
        bins[ch][3] = coarse_bin16(sEL + EL[3] + EL[4] + EL[5],
                                   sEH + EH[3] + EH[4] + EH[5],
                                   sOL + OL[3] + OL[4] + OL[5],
                                   sOH + OH[3] + OH[4] + OH[5]);
    }

    // --- fine phase: per channel, read 27 row words once, 4 selections ---
    uint32_t kk[2][4];
#pragma unroll
    for (int ch = 0; ch < 2; ++ch) {
        const uint32_t* plane = ch ? vP : uP;
        uint32_t rw[27];
#pragma unroll
        for (int r = 0; r < 9; ++r) {
            const uint32_t* row = plane + (ty + r) * US + tx;
            rw[3 * r] = row[0]; rw[3 * r + 1] = row[1]; rw[3 * r + 2] = row[2];
        }
        uint32_t P0[21], P1[21];
        buildP(rw, 0u, P0);
        buildP(rw, 8u, P1);
        fine2(P0, P1, bins[ch][0], bins[ch][1], kk[ch][0], kk[ch][1]);
        buildP(rw, 16u, P0);
        buildP(rw, 24u, P1);
        fine2(P0, P1, bins[ch][2], bins[ch][3], kk[ch][2], kk[ch][3]);
    }

    // --- 3x3 lum median for 4 px via shared column sorts (cols 4tx+3..4tx+8) ---
    float Ym[4];
    {
        const float* lp = &lumT[(ty + 3) * LUMS + 4 * tx + 3];
        float lo[6], mi[6], hi[6];
#pragma unroll
        for (int j = 0; j < 6; ++j) {
            float a = lp[j], b = lp[j + LUMS], c = lp[j + 2 * LUMS];
            cas(a, b); cas(b, c); cas(a, b);
            lo[j] = a; mi[j] = b; hi[j] = c;
        }
#pragma unroll
        for (int p = 0; p < 4; ++p) {
            float mx = fmaxf(fmaxf(lo[p], lo[p + 1]), lo[p + 2]);
            float md = med3(mi[p], mi[p + 1], mi[p + 2]);
            float mn = fminf(fminf(hi[p], hi[p + 1]), hi[p + 2]);
            Ym[p] = fminf(fmaxf(med3(mx, md, mn), 0.0f), 1.0f);
        }
    }

    // --- dequant (bin centers) + YUV->RGB + float4 stores ---
    const float us = (U_HI - U_LO) / NBINS, vs = (V_HI - V_LO) / NBINS;
    float4 Rq, Gq, Bq;
    float* Rp = &Rq.x; float* Gp = &Gq.x; float* Bp = &Bq.x;
#pragma unroll
    for (int p = 0; p < 4; ++p) {
        float Um = U_LO + ((float)kk[0][p] + 0.5f) * us;
        float Vm = V_LO + ((float)kk[1][p] + 0.5f) * vs;
        Rp[p] = Ym[p] + 1.13983f * Vm;
        Gp[p] = Ym[p] - 0.39465f * Um - 0.5806f * Vm;
        Bp[p] = Ym[p] + 2.03211f * Um;
    }
    size_t o = (size_t)bz * IMG3 + (size_t)(by * TH + ty) * W + (bx * TW + 4 * tx);
    *(float4*)(out + o) = Rq;
    *(float4*)(out + o + PLANE) = Gq;
    *(float4*)(out + o + 2 * PLANE) = Bq;
}

} // namespace

extern "C" void kernel_launch(void* const* d_in, const int* in_sizes, int n_in,
                              void* d_out, int out_size, void* d_ws, size_t ws_size,
                              hipStream_t stream) {
    const float* img = (const float*)d_in[0];
    float* out = (float*)d_out;
    int batch = in_sizes[0] / IMG3;  // = 4
    dim3 grid(W / TW, H / TH, batch);
    dim3 block(256);
    hipLaunchKernelGGL(denoise_kernel, grid, block, 0, stream, img, out);
}